// Round 1
// baseline (557.015 us; speedup 1.0000x reference)
//
#include <hip/hip_runtime.h>
#include <hip/hip_bf16.h>
#include <math.h>

typedef __bf16 bf16;
typedef __bf16 bf16x8 __attribute__((ext_vector_type(8)));
typedef float f32x4 __attribute__((ext_vector_type(4)));

#define MFMA16(a, b, c) __builtin_amdgcn_mfma_f32_16x16x32_bf16((a), (b), (c), 0, 0, 0)

constexpr int EMB = 1024;
constexpr int SEQ = 2048;
constexpr int BATCH = 2;
constexpr int NTOK = BATCH * SEQ;   // 4096
constexpr int FFN = 4 * EMB;        // 4096
constexpr int HEADS = 16;
constexpr int HDIM = 64;

// ---------------- LayerNorm: fp32 in -> bf16 out --------------------------
__global__ __launch_bounds__(256) void ln_kernel(const float* __restrict__ x,
                                                 const float* __restrict__ g,
                                                 const float* __restrict__ b,
                                                 bf16* __restrict__ out) {
    int row = blockIdx.x;
    int t = threadIdx.x;
    float4 v = reinterpret_cast<const float4*>(x + (size_t)row * EMB)[t];
    float s = v.x + v.y + v.z + v.w;
    float s2 = v.x * v.x + v.y * v.y + v.z * v.z + v.w * v.w;
#pragma unroll
    for (int o = 1; o < 64; o <<= 1) {
        s += __shfl_xor(s, o);
        s2 += __shfl_xor(s2, o);
    }
    __shared__ float ps[4], ps2[4];
    int w = t >> 6;
    if ((t & 63) == 0) { ps[w] = s; ps2[w] = s2; }
    __syncthreads();
    s = ps[0] + ps[1] + ps[2] + ps[3];
    s2 = ps2[0] + ps2[1] + ps2[2] + ps2[3];
    float mean = s * (1.f / EMB);
    float var = s2 * (1.f / EMB) - mean * mean;
    float rstd = rsqrtf(var + 1e-5f);
    float4 gv = reinterpret_cast<const float4*>(g)[t];
    float4 bv = reinterpret_cast<const float4*>(b)[t];
    bf16* op = out + (size_t)row * EMB + t * 4;
    op[0] = (bf16)(gv.x * (v.x - mean) * rstd + bv.x);
    op[1] = (bf16)(gv.y * (v.y - mean) * rstd + bv.y);
    op[2] = (bf16)(gv.z * (v.z - mean) * rstd + bv.z);
    op[3] = (bf16)(gv.w * (v.w - mean) * rstd + bv.w);
}

// ---------------- transpose + cast: W[K][N] f32 -> Wt[N][K] bf16 ----------
__global__ __launch_bounds__(256) void transpose_cast(const float* __restrict__ W,
                                                      bf16* __restrict__ Wt,
                                                      int K, int N) {
    __shared__ float t[32][33];
    int n0 = blockIdx.x * 32, k0 = blockIdx.y * 32;
    int tx = threadIdx.x, ty = threadIdx.y;  // 32 x 8
#pragma unroll
    for (int i = 0; i < 4; i++)
        t[ty + 8 * i][tx] = W[(size_t)(k0 + ty + 8 * i) * N + n0 + tx];
    __syncthreads();
#pragma unroll
    for (int i = 0; i < 4; i++)
        Wt[(size_t)(n0 + ty + 8 * i) * K + k0 + tx] = (bf16)t[tx][ty + 8 * i];
}

// ---------------- GEMM: C = epi(A[M][K] @ Bt[N][K]^T) ---------------------
// MODE 0: QKV scatter -> bf16 [B,H,S,Dh], value * scale, no bias
// MODE 1: out f32 = resid + acc + bias
// MODE 2: out bf16 = gelu(acc + bias)
template <int MODE>
__global__ __launch_bounds__(256) void gemm_bt(const bf16* __restrict__ A,
                                               const bf16* __restrict__ Bt,
                                               int M, int N, int K,
                                               float* __restrict__ outF,
                                               bf16* __restrict__ outB,
                                               const float* __restrict__ bias,
                                               const float* __restrict__ resid,
                                               float scale) {
    int wave = threadIdx.x >> 6, lane = threadIdx.x & 63;
    int wr = wave >> 1, wc = wave & 1;
    int lr = lane & 15, lg = lane >> 4;
    int row0 = blockIdx.x * 128 + wr * 64;
    int col0 = blockIdx.y * 128 + wc * 64;
    const bf16* Ap = A + (size_t)(row0 + lr) * K + 8 * lg;
    const bf16* Bp = Bt + (size_t)(col0 + lr) * K + 8 * lg;

    f32x4 acc[4][4];
#pragma unroll
    for (int m = 0; m < 4; m++)
#pragma unroll
        for (int n = 0; n < 4; n++) acc[m][n] = f32x4{0.f, 0.f, 0.f, 0.f};

    for (int k = 0; k < K; k += 32) {
        bf16x8 a[4], b[4];
#pragma unroll
        for (int m = 0; m < 4; m++)
            a[m] = *reinterpret_cast<const bf16x8*>(Ap + (size_t)m * 16 * K + k);
#pragma unroll
        for (int n = 0; n < 4; n++)
            b[n] = *reinterpret_cast<const bf16x8*>(Bp + (size_t)n * 16 * K + k);
#pragma unroll
        for (int m = 0; m < 4; m++)
#pragma unroll
            for (int n = 0; n < 4; n++)
                acc[m][n] = MFMA16(a[m], b[n], acc[m][n]);
    }

#pragma unroll
    for (int m = 0; m < 4; m++) {
#pragma unroll
        for (int r = 0; r < 4; r++) {
            int row = row0 + m * 16 + 4 * lg + r;
#pragma unroll
            for (int n = 0; n < 4; n++) {
                int col = col0 + n * 16 + lr;
                float v = acc[m][n][r];
                if (MODE == 0) {
                    int b_ = row >> 11, s_ = row & 2047;
                    int h_ = col >> 6, d_ = col & 63;
                    outB[(((size_t)(b_ * HEADS + h_) * SEQ + s_) << 6) + d_] =
                        (bf16)(v * scale);
                } else if (MODE == 1) {
                    size_t idx = (size_t)row * N + col;
                    outF[idx] = resid[idx] + v + bias[col];
                } else {
                    float u = v + bias[col];
                    float gl = 0.5f * u *
                               (1.f + tanhf(0.7978845608028654f *
                                            (u + 0.044715f * u * u * u)));
                    outB[(size_t)row * N + col] = (bf16)gl;
                }
            }
        }
    }
}

// ---------------- causal flash attention ----------------------------------
// q,k,v: [B,H,S,64] bf16 (q pre-scaled by 1/8); ctx out: [B,S,H*64] bf16
__global__ __launch_bounds__(256) void attn_kernel(const bf16* __restrict__ q,
                                                   const bf16* __restrict__ k,
                                                   const bf16* __restrict__ v,
                                                   bf16* __restrict__ ctx) {
    int bh = blockIdx.y;
    int q0 = blockIdx.x * 64;
    const bf16* qh = q + (size_t)bh * SEQ * HDIM;
    const bf16* kh = k + (size_t)bh * SEQ * HDIM;
    const bf16* vh = v + (size_t)bh * SEQ * HDIM;
    int wave = threadIdx.x >> 6, lane = threadIdx.x & 63;
    int lr = lane & 15, lg = lane >> 4;
    int qrow = q0 + wave * 16;

    bf16x8 qf0 = *reinterpret_cast<const bf16x8*>(qh + (size_t)(qrow + lr) * HDIM + 8 * lg);
    bf16x8 qf1 = *reinterpret_cast<const bf16x8*>(qh + (size_t)(qrow + lr) * HDIM + 32 + 8 * lg);

    f32x4 o[4];
#pragma unroll
    for (int n = 0; n < 4; n++) o[n] = f32x4{0.f, 0.f, 0.f, 0.f};
    float mrow[4] = {-1e30f, -1e30f, -1e30f, -1e30f};
    float lrow[4] = {0.f, 0.f, 0.f, 0.f};

    __shared__ bf16 vt[64][72];          // transposed V chunk
    __shared__ bf16 plds[4][16][72];     // per-wave P

    int kend = q0 + 64;
    for (int c0 = 0; c0 < kend; c0 += 64) {
        __syncthreads();
        {
            int key = threadIdx.x >> 2, d0 = (threadIdx.x & 3) * 16;
            const bf16* vp = vh + (size_t)(c0 + key) * HDIM + d0;
            bf16x8 v0 = *reinterpret_cast<const bf16x8*>(vp);
            bf16x8 v1 = *reinterpret_cast<const bf16x8*>(vp + 8);
#pragma unroll
            for (int e = 0; e < 8; e++) {
                vt[d0 + e][key] = v0[e];
                vt[d0 + 8 + e][key] = v1[e];
            }
        }
        __syncthreads();

        f32x4 sc[4];
#pragma unroll
        for (int kb = 0; kb < 4; kb++) {
            const bf16* kp = kh + (size_t)(c0 + kb * 16 + lr) * HDIM + 8 * lg;
            bf16x8 k0v = *reinterpret_cast<const bf16x8*>(kp);
            bf16x8 k1v = *reinterpret_cast<const bf16x8*>(kp + 32);
            f32x4 t = f32x4{0.f, 0.f, 0.f, 0.f};
            t = MFMA16(qf0, k0v, t);
            t = MFMA16(qf1, k1v, t);
            sc[kb] = t;
        }
        if (c0 == q0) {  // diagonal chunk: causal mask
#pragma unroll
            for (int kb = 0; kb < 4; kb++)
#pragma unroll
                for (int r = 0; r < 4; r++)
                    if (c0 + kb * 16 + lr > qrow + 4 * lg + r) sc[kb][r] = -1e30f;
        }

        float mnew[4], scl[4], psum[4];
#pragma unroll
        for (int r = 0; r < 4; r++) {
            float mp = fmaxf(fmaxf(sc[0][r], sc[1][r]), fmaxf(sc[2][r], sc[3][r]));
#pragma unroll
            for (int off = 1; off < 16; off <<= 1) mp = fmaxf(mp, __shfl_xor(mp, off));
            mnew[r] = fmaxf(mrow[r], mp);
            scl[r] = __expf(mrow[r] - mnew[r]);
            psum[r] = 0.f;
        }
#pragma unroll
        for (int kb = 0; kb < 4; kb++)
#pragma unroll
            for (int r = 0; r < 4; r++) {
                float p = __expf(sc[kb][r] - mnew[r]);
                psum[r] += p;
                plds[wave][4 * lg + r][kb * 16 + lr] = (bf16)p;
            }
#pragma unroll
        for (int r = 0; r < 4; r++) {
            float ps = psum[r];
#pragma unroll
            for (int off = 1; off < 16; off <<= 1) ps += __shfl_xor(ps, off);
            lrow[r] = lrow[r] * scl[r] + ps;
            mrow[r] = mnew[r];
        }
#pragma unroll
        for (int n = 0; n < 4; n++) {
            o[n][0] *= scl[0];
            o[n][1] *= scl[1];
            o[n][2] *= scl[2];
            o[n][3] *= scl[3];
        }
#pragma unroll
        for (int ks = 0; ks < 2; ks++) {
            bf16x8 pa = *reinterpret_cast<const bf16x8*>(&plds[wave][lr][ks * 32 + 8 * lg]);
#pragma unroll
            for (int n = 0; n < 4; n++) {
                bf16x8 bv = *reinterpret_cast<const bf16x8*>(&vt[n * 16 + lr][ks * 32 + 8 * lg]);
                o[n] = MFMA16(pa, bv, o[n]);
            }
        }
    }

    int b_ = bh >> 4, h_ = bh & 15;
#pragma unroll
    for (int r = 0; r < 4; r++) {
        int srow = qrow + 4 * lg + r;
        float inv = 1.f / lrow[r];
        size_t base = ((size_t)b_ * SEQ + srow) * EMB + h_ * HDIM;
#pragma unroll
        for (int n = 0; n < 4; n++) ctx[base + n * 16 + lr] = (bf16)(o[n][r] * inv);
    }
}

// ---------------- launch ---------------------------------------------------
extern "C" void kernel_launch(void* const* d_in, const int* in_sizes, int n_in,
                              void* d_out, int out_size, void* d_ws, size_t ws_size,
                              hipStream_t stream) {
    const float* x  = (const float*)d_in[0];
    const float* Wq = (const float*)d_in[1];
    const float* Wk = (const float*)d_in[2];
    const float* Wv = (const float*)d_in[3];
    const float* Wo = (const float*)d_in[4];
    const float* bo = (const float*)d_in[5];
    const float* W1 = (const float*)d_in[6];
    const float* b1 = (const float*)d_in[7];
    const float* W2 = (const float*)d_in[8];
    const float* b2 = (const float*)d_in[9];
    const float* g1 = (const float*)d_in[10];
    const float* s1 = (const float*)d_in[11];
    const float* g2 = (const float*)d_in[12];
    const float* s2 = (const float*)d_in[13];

    const size_t MB = 1ull << 20;
    char* w = (char*)d_ws;
    bf16* Wqt = (bf16*)(w + 0 * MB);
    bf16* Wkt = (bf16*)(w + 2 * MB);
    bf16* Wvt = (bf16*)(w + 4 * MB);
    bf16* Wot = (bf16*)(w + 6 * MB);
    bf16* W1t = (bf16*)(w + 8 * MB);
    bf16* W2t = (bf16*)(w + 16 * MB);
    bf16* hbuf = (bf16*)(w + 24 * MB);            // h1 / h2 (reused)
    bf16* qb   = (bf16*)(w + 32 * MB);
    bf16* kb   = (bf16*)(w + 40 * MB);
    bf16* vb   = (bf16*)(w + 48 * MB);
    bf16* ctxb = (bf16*)(w + 56 * MB);
    bf16* midb = (bf16*)(w + 32 * MB);            // reuses q/k/v/ctx after attn
    float* x1  = (float*)(w + 64 * MB);

    dim3 tb(32, 8);
    // weight transposes (fp32 -> bf16 [N][K])
    transpose_cast<<<dim3(EMB / 32, EMB / 32), tb, 0, stream>>>(Wq, Wqt, EMB, EMB);
    transpose_cast<<<dim3(EMB / 32, EMB / 32), tb, 0, stream>>>(Wk, Wkt, EMB, EMB);
    transpose_cast<<<dim3(EMB / 32, EMB / 32), tb, 0, stream>>>(Wv, Wvt, EMB, EMB);
    transpose_cast<<<dim3(EMB / 32, EMB / 32), tb, 0, stream>>>(Wo, Wot, EMB, EMB);
    transpose_cast<<<dim3(FFN / 32, EMB / 32), tb, 0, stream>>>(W1, W1t, EMB, FFN);
    transpose_cast<<<dim3(EMB / 32, FFN / 32), tb, 0, stream>>>(W2, W2t, FFN, EMB);

    // LN1
    ln_kernel<<<NTOK, 256, 0, stream>>>(x, g1, s1, hbuf);

    // QKV projections (q scaled by 1/sqrt(64))
    gemm_bt<0><<<dim3(NTOK / 128, EMB / 128), 256, 0, stream>>>(
        hbuf, Wqt, NTOK, EMB, EMB, nullptr, qb, nullptr, nullptr, 0.125f);
    gemm_bt<0><<<dim3(NTOK / 128, EMB / 128), 256, 0, stream>>>(
        hbuf, Wkt, NTOK, EMB, EMB, nullptr, kb, nullptr, nullptr, 1.0f);
    gemm_bt<0><<<dim3(NTOK / 128, EMB / 128), 256, 0, stream>>>(
        hbuf, Wvt, NTOK, EMB, EMB, nullptr, vb, nullptr, nullptr, 1.0f);

    // attention
    attn_kernel<<<dim3(SEQ / 64, BATCH * HEADS), 256, 0, stream>>>(qb, kb, vb, ctxb);

    // output projection + residual -> x1 (f32)
    gemm_bt<1><<<dim3(NTOK / 128, EMB / 128), 256, 0, stream>>>(
        ctxb, Wot, NTOK, EMB, EMB, x1, nullptr, bo, x, 1.0f);

    // LN2
    ln_kernel<<<NTOK, 256, 0, stream>>>(x1, g2, s2, hbuf);

    // FFN1 + gelu -> bf16 mid
    gemm_bt<2><<<dim3(NTOK / 128, FFN / 128), 256, 0, stream>>>(
        hbuf, W1t, NTOK, FFN, EMB, nullptr, midb, b1, nullptr, 1.0f);

    // FFN2 + bias + residual -> d_out (f32)
    gemm_bt<1><<<dim3(NTOK / 128, EMB / 128), 256, 0, stream>>>(
        midb, W2t, NTOK, EMB, FFN, (float*)d_out, nullptr, b2, x1, 1.0f);
}

// Round 2
// 376.857 us; speedup vs baseline: 1.4781x; 1.4781x over previous
//
#include <hip/hip_runtime.h>
#include <hip/hip_bf16.h>
#include <math.h>
#include <stdint.h>

typedef __bf16 bf16;
typedef __bf16 bf16x8 __attribute__((ext_vector_type(8)));
typedef float f32x4 __attribute__((ext_vector_type(4)));

#define MFMA16(a, b, c) __builtin_amdgcn_mfma_f32_16x16x32_bf16((a), (b), (c), 0, 0, 0)

constexpr int EMB = 1024;
constexpr int SEQ = 2048;
constexpr int BATCH = 2;
constexpr int NTOK = BATCH * SEQ;   // 4096
constexpr int FFN = 4 * EMB;        // 4096
constexpr int HEADS = 16;
constexpr int HDIM = 64;

// async 16B global -> LDS (wave-uniform base + lane*16 destination)
__device__ __forceinline__ void gload16(const void* g, void* l) {
    __builtin_amdgcn_global_load_lds(
        (const __attribute__((address_space(1))) void*)g,
        (__attribute__((address_space(3))) void*)l,
        16, 0, 0);
}

// ---------------- LayerNorm: fp32 in -> bf16 out --------------------------
__global__ __launch_bounds__(256) void ln_kernel(const float* __restrict__ x,
                                                 const float* __restrict__ g,
                                                 const float* __restrict__ b,
                                                 bf16* __restrict__ out) {
    int row = blockIdx.x;
    int t = threadIdx.x;
    float4 v = reinterpret_cast<const float4*>(x + (size_t)row * EMB)[t];
    float s = v.x + v.y + v.z + v.w;
    float s2 = v.x * v.x + v.y * v.y + v.z * v.z + v.w * v.w;
#pragma unroll
    for (int o = 1; o < 64; o <<= 1) {
        s += __shfl_xor(s, o);
        s2 += __shfl_xor(s2, o);
    }
    __shared__ float ps[4], ps2[4];
    int w = t >> 6;
    if ((t & 63) == 0) { ps[w] = s; ps2[w] = s2; }
    __syncthreads();
    s = ps[0] + ps[1] + ps[2] + ps[3];
    s2 = ps2[0] + ps2[1] + ps2[2] + ps2[3];
    float mean = s * (1.f / EMB);
    float var = s2 * (1.f / EMB) - mean * mean;
    float rstd = rsqrtf(var + 1e-5f);
    float4 gv = reinterpret_cast<const float4*>(g)[t];
    float4 bv = reinterpret_cast<const float4*>(b)[t];
    bf16* op = out + (size_t)row * EMB + t * 4;
    op[0] = (bf16)(gv.x * (v.x - mean) * rstd + bv.x);
    op[1] = (bf16)(gv.y * (v.y - mean) * rstd + bv.y);
    op[2] = (bf16)(gv.z * (v.z - mean) * rstd + bv.z);
    op[3] = (bf16)(gv.w * (v.w - mean) * rstd + bv.w);
}

// ---------------- transpose + cast: W[K][N] f32 -> Wt[N][K] bf16 ----------
__global__ __launch_bounds__(256) void transpose_cast(const float* __restrict__ W,
                                                      bf16* __restrict__ Wt,
                                                      int K, int N) {
    __shared__ float t[32][33];
    int n0 = blockIdx.x * 32, k0 = blockIdx.y * 32;
    int tx = threadIdx.x, ty = threadIdx.y;  // 32 x 8
#pragma unroll
    for (int i = 0; i < 4; i++)
        t[ty + 8 * i][tx] = W[(size_t)(k0 + ty + 8 * i) * N + n0 + tx];
    __syncthreads();
#pragma unroll
    for (int i = 0; i < 4; i++)
        Wt[(size_t)(n0 + ty + 8 * i) * K + k0 + tx] = (bf16)t[tx][ty + 8 * i];
}

// ---------------- LDS-staged GEMM (m97 structure) -------------------------
// C = epi(A[M][K] @ Bt[N][K]^T), BK=32, 4 waves in 2x2, per-wave (BM/2)x(BN/2)
// MODE 0: fused QKV scatter -> bf16 q/k/v [B,H,S,64] (q scaled 1/8)
// MODE 1: out f32 = resid + acc + bias
// MODE 2: out bf16 = gelu(acc + bias)
template <int BM, int BN, int MODE>
__global__ __launch_bounds__(256) void gemm_lds(const bf16* __restrict__ A,
                                                const bf16* __restrict__ Bt,
                                                int M, int N, int K,
                                                float* __restrict__ outF,
                                                bf16* __restrict__ outB,
                                                const float* __restrict__ bias,
                                                const float* __restrict__ resid) {
    constexpr int MR = BM / 32;              // M frags per wave
    constexpr int NR = BN / 32;              // N frags per wave
    constexpr int ACH = (BM * 64) / 4096;    // 16B chunks/thread for A tile
    constexpr int BCH = (BN * 64) / 4096;
    __shared__ bf16 sA[BM * 32];
    __shared__ bf16 sB[BN * 32];
    int t = threadIdx.x;
    int wave = t >> 6, lane = t & 63;
    int wr = wave >> 1, wc = wave & 1;
    int lr = lane & 15, lg = lane >> 4;
    int row0 = blockIdx.x * BM;
    int col0 = blockIdx.y * BN;

    // staging source pointers (advance 64B per K-step)
    const char* aS[ACH];
    const char* bS[BCH];
#pragma unroll
    for (int c = 0; c < ACH; c++) {
        int o = (t + c * 256) * 16;
        aS[c] = (const char*)A + (size_t)(row0 + (o >> 6)) * K * 2 + (o & 63);
    }
#pragma unroll
    for (int c = 0; c < BCH; c++) {
        int o = (t + c * 256) * 16;
        bS[c] = (const char*)Bt + (size_t)(col0 + (o >> 6)) * K * 2 + (o & 63);
    }

    f32x4 acc[MR][NR];
#pragma unroll
    for (int m = 0; m < MR; m++)
#pragma unroll
        for (int n = 0; n < NR; n++) acc[m][n] = f32x4{0.f, 0.f, 0.f, 0.f};

    for (int k0 = 0; k0 < K; k0 += 32) {
        __syncthreads();
#pragma unroll
        for (int c = 0; c < ACH; c++)
            gload16(aS[c], (char*)sA + (t + c * 256) * 16);
#pragma unroll
        for (int c = 0; c < BCH; c++)
            gload16(bS[c], (char*)sB + (t + c * 256) * 16);
#pragma unroll
        for (int c = 0; c < ACH; c++) aS[c] += 64;
#pragma unroll
        for (int c = 0; c < BCH; c++) bS[c] += 64;
        __syncthreads();

        bf16x8 a[MR], b[NR];
#pragma unroll
        for (int m = 0; m < MR; m++)
            a[m] = *reinterpret_cast<const bf16x8*>(
                sA + (wr * (BM / 2) + m * 16 + lr) * 32 + 8 * lg);
#pragma unroll
        for (int n = 0; n < NR; n++)
            b[n] = *reinterpret_cast<const bf16x8*>(
                sB + (wc * (BN / 2) + n * 16 + lr) * 32 + 8 * lg);
#pragma unroll
        for (int m = 0; m < MR; m++)
#pragma unroll
            for (int n = 0; n < NR; n++)
                acc[m][n] = MFMA16(a[m], b[n], acc[m][n]);
    }

#pragma unroll
    for (int m = 0; m < MR; m++) {
#pragma unroll
        for (int r = 0; r < 4; r++) {
            int row = row0 + wr * (BM / 2) + m * 16 + 4 * lg + r;
#pragma unroll
            for (int n = 0; n < NR; n++) {
                int col = col0 + wc * (BN / 2) + n * 16 + lr;
                float v = acc[m][n][r];
                if (MODE == 0) {
                    int b_ = row >> 11, s_ = row & 2047;
                    int which = col >> 10, rem = col & 1023;
                    int h_ = rem >> 6, d_ = rem & 63;
                    float sc = (which == 0) ? 0.125f : 1.0f;
                    outB[(size_t)which * (NTOK * EMB) +
                         (((size_t)(b_ * HEADS + h_) * SEQ + s_) << 6) + d_] =
                        (bf16)(v * sc);
                } else if (MODE == 1) {
                    size_t idx = (size_t)row * N + col;
                    outF[idx] = resid[idx] + v + bias[col];
                } else {
                    float u = v + bias[col];
                    float gl = 0.5f * u *
                               (1.f + tanhf(0.7978845608028654f *
                                            (u + 0.044715f * u * u * u)));
                    outB[(size_t)row * N + col] = (bf16)gl;
                }
            }
        }
    }
}

// ---------------- causal flash attention ----------------------------------
// q,k,v: [B,H,S,64] bf16 (q pre-scaled by 1/8); ctx out: [B,S,H*64] bf16
__global__ __launch_bounds__(256) void attn_kernel(const bf16* __restrict__ q,
                                                   const bf16* __restrict__ k,
                                                   const bf16* __restrict__ v,
                                                   bf16* __restrict__ ctx) {
    int bh = blockIdx.y;
    int q0 = blockIdx.x * 64;
    const bf16* qh = q + (size_t)bh * SEQ * HDIM;
    const bf16* kh = k + (size_t)bh * SEQ * HDIM;
    const bf16* vh = v + (size_t)bh * SEQ * HDIM;
    int wave = threadIdx.x >> 6, lane = threadIdx.x & 63;
    int lr = lane & 15, lg = lane >> 4;
    int qrow = q0 + wave * 16;

    bf16x8 qf0 = *reinterpret_cast<const bf16x8*>(qh + (size_t)(qrow + lr) * HDIM + 8 * lg);
    bf16x8 qf1 = *reinterpret_cast<const bf16x8*>(qh + (size_t)(qrow + lr) * HDIM + 32 + 8 * lg);

    f32x4 o[4];
#pragma unroll
    for (int n = 0; n < 4; n++) o[n] = f32x4{0.f, 0.f, 0.f, 0.f};
    float mrow[4] = {-1e30f, -1e30f, -1e30f, -1e30f};
    float lrow[4] = {0.f, 0.f, 0.f, 0.f};

    __shared__ bf16 vt[64][72];          // transposed V chunk
    __shared__ bf16 plds[4][16][72];     // per-wave P

    int kend = q0 + 64;
    for (int c0 = 0; c0 < kend; c0 += 64) {
        __syncthreads();
        {
            int key = threadIdx.x >> 2, d0 = (threadIdx.x & 3) * 16;
            const bf16* vp = vh + (size_t)(c0 + key) * HDIM + d0;
            bf16x8 v0 = *reinterpret_cast<const bf16x8*>(vp);
            bf16x8 v1 = *reinterpret_cast<const bf16x8*>(vp + 8);
#pragma unroll
            for (int e = 0; e < 8; e++) {
                vt[d0 + e][key] = v0[e];
                vt[d0 + 8 + e][key] = v1[e];
            }
        }
        __syncthreads();

        f32x4 sc[4];
#pragma unroll
        for (int kb = 0; kb < 4; kb++) {
            const bf16* kp = kh + (size_t)(c0 + kb * 16 + lr) * HDIM + 8 * lg;
            bf16x8 k0v = *reinterpret_cast<const bf16x8*>(kp);
            bf16x8 k1v = *reinterpret_cast<const bf16x8*>(kp + 32);
            f32x4 t = f32x4{0.f, 0.f, 0.f, 0.f};
            t = MFMA16(qf0, k0v, t);
            t = MFMA16(qf1, k1v, t);
            sc[kb] = t;
        }
        if (c0 == q0) {  // diagonal chunk: causal mask
#pragma unroll
            for (int kb = 0; kb < 4; kb++)
#pragma unroll
                for (int r = 0; r < 4; r++)
                    if (c0 + kb * 16 + lr > qrow + 4 * lg + r) sc[kb][r] = -1e30f;
        }

        float mnew[4], scl[4], psum[4];
#pragma unroll
        for (int r = 0; r < 4; r++) {
            float mp = fmaxf(fmaxf(sc[0][r], sc[1][r]), fmaxf(sc[2][r], sc[3][r]));
#pragma unroll
            for (int off = 1; off < 16; off <<= 1) mp = fmaxf(mp, __shfl_xor(mp, off));
            mnew[r] = fmaxf(mrow[r], mp);
            scl[r] = __expf(mrow[r] - mnew[r]);
            psum[r] = 0.f;
        }
#pragma unroll
        for (int kb = 0; kb < 4; kb++)
#pragma unroll
            for (int r = 0; r < 4; r++) {
                float p = __expf(sc[kb][r] - mnew[r]);
                psum[r] += p;
                plds[wave][4 * lg + r][kb * 16 + lr] = (bf16)p;
            }
#pragma unroll
        for (int r = 0; r < 4; r++) {
            float ps = psum[r];
#pragma unroll
            for (int off = 1; off < 16; off <<= 1) ps += __shfl_xor(ps, off);
            lrow[r] = lrow[r] * scl[r] + ps;
            mrow[r] = mnew[r];
        }
#pragma unroll
        for (int n = 0; n < 4; n++) {
            o[n][0] *= scl[0];
            o[n][1] *= scl[1];
            o[n][2] *= scl[2];
            o[n][3] *= scl[3];
        }
#pragma unroll
        for (int ks = 0; ks < 2; ks++) {
            bf16x8 pa = *reinterpret_cast<const bf16x8*>(&plds[wave][lr][ks * 32 + 8 * lg]);
#pragma unroll
            for (int n = 0; n < 4; n++) {
                bf16x8 bv = *reinterpret_cast<const bf16x8*>(&vt[n * 16 + lr][ks * 32 + 8 * lg]);
                o[n] = MFMA16(pa, bv, o[n]);
            }
        }
    }

    int b_ = bh >> 4, h_ = bh & 15;
#pragma unroll
    for (int r = 0; r < 4; r++) {
        int srow = qrow + 4 * lg + r;
        float inv = 1.f / lrow[r];
        size_t base = ((size_t)b_ * SEQ + srow) * EMB + h_ * HDIM;
#pragma unroll
        for (int n = 0; n < 4; n++) ctx[base + n * 16 + lr] = (bf16)(o[n][r] * inv);
    }
}

// ---------------- launch ---------------------------------------------------
extern "C" void kernel_launch(void* const* d_in, const int* in_sizes, int n_in,
                              void* d_out, int out_size, void* d_ws, size_t ws_size,
                              hipStream_t stream) {
    const float* x  = (const float*)d_in[0];
    const float* Wq = (const float*)d_in[1];
    const float* Wk = (const float*)d_in[2];
    const float* Wv = (const float*)d_in[3];
    const float* Wo = (const float*)d_in[4];
    const float* bo = (const float*)d_in[5];
    const float* W1 = (const float*)d_in[6];
    const float* b1 = (const float*)d_in[7];
    const float* W2 = (const float*)d_in[8];
    const float* b2 = (const float*)d_in[9];
    const float* g1 = (const float*)d_in[10];
    const float* s1 = (const float*)d_in[11];
    const float* g2 = (const float*)d_in[12];
    const float* s2 = (const float*)d_in[13];

    const size_t MB = 1ull << 20;
    char* w = (char*)d_ws;
    bf16* Wqkvt = (bf16*)(w + 0 * MB);            // [3072][1024] contiguous
    bf16* Wqt = Wqkvt;
    bf16* Wkt = (bf16*)(w + 2 * MB);
    bf16* Wvt = (bf16*)(w + 4 * MB);
    bf16* Wot = (bf16*)(w + 6 * MB);
    bf16* W1t = (bf16*)(w + 8 * MB);
    bf16* W2t = (bf16*)(w + 16 * MB);
    bf16* hbuf = (bf16*)(w + 24 * MB);            // h1 / h2 (reused)
    bf16* qkvb = (bf16*)(w + 32 * MB);            // q @32, k @40, v @48 MB
    bf16* qb   = (bf16*)(w + 32 * MB);
    bf16* kb   = (bf16*)(w + 40 * MB);
    bf16* vb   = (bf16*)(w + 48 * MB);
    bf16* ctxb = (bf16*)(w + 56 * MB);
    bf16* midb = (bf16*)(w + 32 * MB);            // reuses qkv after attn
    float* x1  = (float*)(w + 64 * MB);

    dim3 tb(32, 8);
    // weight transposes (fp32 -> bf16 [N][K]); Wq/Wk/Wv contiguous
    transpose_cast<<<dim3(EMB / 32, EMB / 32), tb, 0, stream>>>(Wq, Wqt, EMB, EMB);
    transpose_cast<<<dim3(EMB / 32, EMB / 32), tb, 0, stream>>>(Wk, Wkt, EMB, EMB);
    transpose_cast<<<dim3(EMB / 32, EMB / 32), tb, 0, stream>>>(Wv, Wvt, EMB, EMB);
    transpose_cast<<<dim3(EMB / 32, EMB / 32), tb, 0, stream>>>(Wo, Wot, EMB, EMB);
    transpose_cast<<<dim3(FFN / 32, EMB / 32), tb, 0, stream>>>(W1, W1t, EMB, FFN);
    transpose_cast<<<dim3(EMB / 32, FFN / 32), tb, 0, stream>>>(W2, W2t, FFN, EMB);

    // LN1
    ln_kernel<<<NTOK, 256, 0, stream>>>(x, g1, s1, hbuf);

    // fused QKV projection: [4096,1024] @ [3072,1024]^T
    gemm_lds<128, 128, 0><<<dim3(NTOK / 128, 3072 / 128), 256, 0, stream>>>(
        hbuf, Wqkvt, NTOK, 3072, EMB, nullptr, qkvb, nullptr, nullptr);

    // attention
    attn_kernel<<<dim3(SEQ / 64, BATCH * HEADS), 256, 0, stream>>>(qb, kb, vb, ctxb);

    // output projection + residual -> x1 (f32)
    gemm_lds<128, 64, 1><<<dim3(NTOK / 128, EMB / 64), 256, 0, stream>>>(
        ctxb, Wot, NTOK, EMB, EMB, x1, nullptr, bo, x);

    // LN2
    ln_kernel<<<NTOK, 256, 0, stream>>>(x1, g2, s2, hbuf);

    // FFN1 + gelu -> bf16 mid
    gemm_lds<128, 128, 2><<<dim3(NTOK / 128, FFN / 128), 256, 0, stream>>>(
        hbuf, W1t, NTOK, FFN, EMB, nullptr, midb, b1, nullptr);

    // FFN2 + bias + residual -> d_out (f32)
    gemm_lds<128, 64, 1><<<dim3(NTOK / 128, EMB / 64), 256, 0, stream>>>(
        midb, W2t, NTOK, EMB, FFN, (float*)d_out, nullptr, b2, x1);
}